// Round 6
// baseline (330.907 us; speedup 1.0000x reference)
//
#include <hip/hip_runtime.h>

#define KCODES 512
#define DIM    64
#define PXB    64          // pixels per block
#define NW     8           // waves per block (512 threads)

typedef __attribute__((ext_vector_type(8))) short  short8;   // 8 bf16 = 4 VGPRs
typedef __attribute__((ext_vector_type(4))) float  floatx4;  // MFMA C/D

__device__ inline unsigned short f2bf(float x) {             // RNE fp32->bf16
    unsigned u = __float_as_uint(x);
    return (unsigned short)((u + 0x7FFFu + ((u >> 16) & 1u)) >> 16);
}
__device__ inline float bf2f(unsigned short h) { return __uint_as_float(((unsigned)h) << 16); }

// --- prep (single dispatch): enorm + (-2e) hi/lo bf16 + zero counts/done --
__global__ __launch_bounds__(256) void vq_prep(const float* __restrict__ e,
        float* __restrict__ enorm, unsigned short* __restrict__ ehs,
        unsigned short* __restrict__ els, float* __restrict__ counts,
        unsigned* __restrict__ done) {
    int j = blockIdx.x * 256 + threadIdx.x;    // 0..511 (one code row)
    const float4* er = (const float4*)(e + (size_t)j * DIM);
    short8* eh8 = (short8*)(ehs + (size_t)j * DIM);
    short8* el8 = (short8*)(els + (size_t)j * DIM);
    float s = 0.f;
    #pragma unroll
    for (int k = 0; k < 8; ++k) {
        float4 a = er[2 * k], bq = er[2 * k + 1];
        float vv[8] = {a.x, a.y, a.z, a.w, bq.x, bq.y, bq.z, bq.w};
        short8 hi, lo;
        #pragma unroll
        for (int i = 0; i < 8; ++i) {
            s = fmaf(vv[i], vv[i], s);         // ascending d: same order as R5
            float x = -2.f * vv[i];
            unsigned short h = f2bf(x);
            hi[i] = (short)h;
            lo[i] = (short)f2bf(x - bf2f(h));
        }
        eh8[k] = hi; el8[k] = lo;
    }
    enorm[j] = s;
    counts[j] = 0.f;
    if (j == 0) *done = 0u;
}

// --- main: 512 thr / 8 waves; wave owns 64 codes (A-frags 64 regs);
// 64 px staged in LDS as hi/lo bf16; enorm in LDS (broadcast reads).
// Scores via 16x16x32 bf16 MFMA, 3-pass hi/lo (bit-exact argmin vs fp32, R5).
// EMA epilogue fused via last-block ticket.
__global__ __launch_bounds__(512, 4) void vq_main(
        const float* __restrict__ z, const float* __restrict__ e,
        const unsigned short* __restrict__ ehs, const unsigned short* __restrict__ els,
        const float* __restrict__ enorm, const float* __restrict__ Nin,
        float* __restrict__ zq, float* __restrict__ counts,
        unsigned* __restrict__ done)
{
    // pixel slot padded: pxp = px + (px>>3) -> 72 slots (kills 8-way b128 conflict)
    __shared__ __align__(16) short lz[2][8][72][8];   // 18.4 KB [hi/lo][dim8][pxp][8]
    __shared__ float enorm_s[KCODES];                 // 2 KB
    __shared__ float red_v[NW][PXB];                  // 2 KB
    __shared__ int   red_i[NW][PXB];                  // 2 KB
    __shared__ int   hist[KCODES];                    // 2 KB
    __shared__ int   lastflag;

    const int b    = blockIdx.x;
    const int t    = threadIdx.x;
    const int w    = t >> 6;        // wave id = dim-chunk for staging/gather
    const int lane = t & 63;
    const int n16  = lane & 15;
    const int g4   = lane >> 4;

    hist[t] = 0;
    enorm_s[t] = enorm[t];

    // ---- stage z: wave w loads dims 8w..8w+7 for all 64 px (coalesced) ----
    const int px0 = t & 63;
    const int gp  = b * PXB + px0;
    const int bb  = gp >> 8, hw = gp & 255;
    {
        const float* zrow = z + (size_t)bb * (DIM * 256) + hw;
        float v[8];
        #pragma unroll
        for (int i = 0; i < 8; ++i) v[i] = zrow[(size_t)(8 * w + i) * 256];
        short8 hi, lo;
        #pragma unroll
        for (int i = 0; i < 8; ++i) {
            unsigned short h = f2bf(v[i]);
            hi[i] = (short)h;
            lo[i] = (short)f2bf(v[i] - bf2f(h));
        }
        const int pxp = px0 + (px0 >> 3);
        *(short8*)(&lz[0][w][pxp][0]) = hi;
        *(short8*)(&lz[1][w][pxp][0]) = lo;
    }

    // ---- A-fragments: wave owns codes w*64 .. +63 (4 tiles of 16) ----
    const int wbase = w * 64;
    short8 eH[4][2], eL[4][2];
    #pragma unroll
    for (int ct = 0; ct < 4; ++ct) {
        const size_t crow = (size_t)(wbase + ct * 16 + n16) * DIM + g4 * 8;
        #pragma unroll
        for (int ks = 0; ks < 2; ++ks) {
            eH[ct][ks] = *(const short8*)(ehs + crow + ks * 32);
            eL[ct][ks] = *(const short8*)(els + crow + ks * 32);
        }
    }

    __syncthreads();

    #pragma unroll
    for (int pt = 0; pt < 4; ++pt) {
        const int px  = pt * 16 + n16;
        const int pxp = px + (px >> 3);
        short8 bh0 = *(short8*)(&lz[0][g4    ][pxp][0]);
        short8 bh1 = *(short8*)(&lz[0][4 + g4][pxp][0]);
        short8 bl0 = *(short8*)(&lz[1][g4    ][pxp][0]);
        short8 bl1 = *(short8*)(&lz[1][4 + g4][pxp][0]);

        float bestv = 3.4e38f;
        int   besti = 0;
        #pragma unroll
        for (int ct = 0; ct < 4; ++ct) {
            float4 en4 = *(const float4*)(&enorm_s[wbase + ct * 16 + g4 * 4]);
            floatx4 C = {en4.x, en4.y, en4.z, en4.w};
            C = __builtin_amdgcn_mfma_f32_16x16x32_bf16(eL[ct][0], bh0, C, 0, 0, 0);
            C = __builtin_amdgcn_mfma_f32_16x16x32_bf16(eL[ct][1], bh1, C, 0, 0, 0);
            C = __builtin_amdgcn_mfma_f32_16x16x32_bf16(eH[ct][0], bl0, C, 0, 0, 0);
            C = __builtin_amdgcn_mfma_f32_16x16x32_bf16(eH[ct][1], bl1, C, 0, 0, 0);
            C = __builtin_amdgcn_mfma_f32_16x16x32_bf16(eH[ct][0], bh0, C, 0, 0, 0);
            C = __builtin_amdgcn_mfma_f32_16x16x32_bf16(eH[ct][1], bh1, C, 0, 0, 0);
            #pragma unroll
            for (int r = 0; r < 4; ++r) {     // ascending id + strict <
                float s = C[r];                // == numpy first-min tie-break
                int  id = wbase + ct * 16 + g4 * 4 + r;
                if (s < bestv) { bestv = s; besti = id; }
            }
        }
        float v1 = __shfl_down(bestv, 32); int i1 = __shfl_down(besti, 32);
        if (v1 < bestv || (v1 == bestv && i1 < besti)) { bestv = v1; besti = i1; }
        v1 = __shfl_down(bestv, 16); i1 = __shfl_down(besti, 16);
        if (v1 < bestv || (v1 == bestv && i1 < besti)) { bestv = v1; besti = i1; }
        if (lane < 16) { red_v[w][px] = bestv; red_i[w][px] = besti; }
    }

    __syncthreads();

    // ---- combine 8 waves per pixel, histogram, publish final index ----
    if (t < PXB) {
        float bv = red_v[0][t]; int bi = red_i[0][t];
        #pragma unroll
        for (int ww = 1; ww < NW; ++ww) {
            float v = red_v[ww][t]; int i = red_i[ww][t];
            if (v < bv || (v == bv && i < bi)) { bv = v; bi = i; }
        }
        atomicAdd(&hist[bi], 1);
        red_i[0][t] = bi;
    }
    __syncthreads();

    // ---- gather: wave w writes dims 8w..8w+7 of pixel px0 (coalesced) ----
    {
        const int bi = red_i[0][px0];
        const float4* er4 = (const float4*)(e + (size_t)bi * DIM + 8 * w);
        float* ob = zq + (size_t)bb * (DIM * 256) + (size_t)(8 * w) * 256 + hw;
        float4 va = er4[0], vb = er4[1];
        ob[0]        = va.x; ob[256]      = va.y; ob[512]      = va.z; ob[768]      = va.w;
        ob[1024]     = vb.x; ob[1280]     = vb.y; ob[1536]     = vb.z; ob[1792]     = vb.w;
    }

    int h = hist[t];
    if (h) atomicAdd(&counts[t], (float)h);

    __syncthreads();                      // barrier drains this block's atomics
    if (t == 0) {
        __threadfence();                  // device-scope release before ticket
        lastflag = (atomicAdd(done, 1u) == (unsigned)(gridDim.x - 1)) ? 1 : 0;
    }
    __syncthreads();
    if (lastflag) {                       // last block: EMA epilogue (t == code)
        float cfin = atomicAdd(&counts[t], 0.0f);   // device-scope atomic read
        // outN lives right after zq in d_out; zq size = gridDim*PXB*DIM
        float* outN = zq + (size_t)gridDim.x * PXB * DIM;
        outN[t] = 0.995f * Nin[t] + 0.005f * cfin;
    }
}

extern "C" void kernel_launch(void* const* d_in, const int* in_sizes, int n_in,
                              void* d_out, int out_size, void* d_ws, size_t ws_size,
                              hipStream_t stream) {
    const float* z = (const float*)d_in[0];
    const float* e = (const float*)d_in[1];
    const float* N = (const float*)d_in[2];
    float* out = (float*)d_out;
    const int nz     = in_sizes[0];            // B*D*H*W = 16777216
    const int npix   = nz / DIM;               // 262144
    const int blocks = npix / PXB;             // 4096

    char* ws = (char*)d_ws;
    float*          enorm  = (float*)(ws);                  // 512 f
    float*          counts = (float*)(ws + 2048);           // 512 f
    unsigned*       done   = (unsigned*)(ws + 4096);        // 1 u32 (pad 256B)
    unsigned short* ehs    = (unsigned short*)(ws + 4352);  // 32768 u16
    unsigned short* els    = (unsigned short*)(ws + 4352 + KCODES * DIM * 2);

    vq_prep<<<2, 256, 0, stream>>>(e, enorm, ehs, els, counts, done);
    vq_main<<<blocks, 512, 0, stream>>>(z, e, ehs, els, enorm, N, out, counts, done);
}